// Round 8
// baseline (2171.984 us; speedup 1.0000x reference)
//
#include <hip/hip_runtime.h>
#include <math.h>

#define N_ROWS 65536
#define CB 1024
#define SPLITS 4
#define JS (CB / SPLITS)     // 256 codebook entries per split
#define NFILLER 1024         // zero-filler blocks (bids 0..1023), ONE slice each
#define SLICE_F 196608       // floats per 64-row slice of out3 (64*3*1024)

typedef float v4f __attribute__((ext_vector_type(4)));

// ---------------------------------------------------------------------------
// Exact emulation of numpy's pairwise_sum for n=64 fp32 (AVX-512 path).
// fp contract OFF so the squares are not fused into the adds.
// ---------------------------------------------------------------------------
__device__ __forceinline__ float tree_sum64_sq(const float* x) {
#pragma clang fp contract(off)
    float sq[64];
#pragma unroll
    for (int i = 0; i < 64; ++i) sq[i] = x[i] * x[i];
    float s[16];
#pragma unroll
    for (int l = 0; l < 16; ++l) s[l] = (sq[l] + sq[l + 16]) + (sq[l + 32] + sq[l + 48]);
    float t[8];
#pragma unroll
    for (int l = 0; l < 8; ++l) t[l] = s[l] + s[l + 8];
    float u[4];
#pragma unroll
    for (int l = 0; l < 4; ++l) u[l] = t[l] + t[l + 4];
    float v0 = u[0] + u[2];
    float v1 = u[1] + u[3];
    return v0 + v1;
}

// sorted-triple insert, strict < (ties keep earlier-inserted = lower index,
// matching jax.lax.top_k stable tie-breaking when fed in ascending index order)
__device__ __forceinline__ void top3_insert(float d, int j,
                                            float& v0, float& v1, float& v2,
                                            int& i0, int& i1, int& i2) {
    bool b0 = d < v0, b1 = d < v1, b2 = d < v2;
    v2 = b1 ? v1 : (b2 ? d : v2);
    i2 = b1 ? i1 : (b2 ? j : i2);
    v1 = b0 ? v0 : (b1 ? d : v1);
    i1 = b0 ? i0 : (b1 ? j : i1);
    v0 = b0 ? d : v0;
    i0 = b0 ? j : i0;
}

// ---------------------------------------------------------------------------
// B[j] = np.sum(emb[j]**2) (exact tree emulation) + zero hist/lossAcc/flags.
// flags[1024]: one per 64-row slice of out3. 0=unfilled, 3=filler writing,
// 1=zeros durable, 2=claimed by scorer fallback.
// ---------------------------------------------------------------------------
__global__ __launch_bounds__(256) void prep_kernel(const float* __restrict__ emb,
                                                   float* __restrict__ B,
                                                   int* __restrict__ hist,
                                                   float* __restrict__ lossAcc,
                                                   int* __restrict__ flags) {
    int j = blockIdx.x * 256 + threadIdx.x;
    if (j >= CB) return;
    float e[64];
    const float4* e4 = (const float4*)(emb + (size_t)j * 64);
#pragma unroll
    for (int k = 0; k < 16; ++k) {
        float4 v = e4[k];
        e[4 * k] = v.x; e[4 * k + 1] = v.y; e[4 * k + 2] = v.z; e[4 * k + 3] = v.w;
    }
    B[j] = tree_sum64_sq(e);
    hist[j] = 0;
    flags[j] = 0;
    if (j == 0) *lossAcc = 0.0f;
}

// ---------------------------------------------------------------------------
// Single dispatch, two roles. R7's producer/consumer structure was sound but
// STARVED: 1024 filler waves x 63 outstanding x 16B = ~1 MB in flight ->
// Little's-law cap ~1.5 TB/s (measured 1.53), dragging the kernel to 554 us.
// This round: 1024 filler BLOCKS (4096 waves, ~4 MB in flight -> cap ~4 TB/s,
// i.e. the real ~2.6 TB/s chip write wall becomes the limit).
//
//  bids [0,1024):     FILLER blocks — each zeroes ONE 786 KB slice of out3.
//                     CAS(0->3) claim, zero, fence, release flag=1.
//  bids [1024,2048):  SCORER blocks — unchanged bit-exact score/merge/
//                     epilogue; acquire-spin on slice flag, scatter <=192
//                     ones. Bounded spin -> CAS(0->2) self-fill fallback.
//
// __launch_bounds__(256,8): 8 blocks/CU -> all 2048 blocks co-resident
// (per CU: 4 fillers + 4 scorers; VGPR cap 64 >= measured 48).
// Cross-XCD visibility: filler __threadfence + agent release store; scorer
// agent acquire load + threadfence (per-XCD L2s non-coherent).
// ---------------------------------------------------------------------------
__global__ __launch_bounds__(256, 8) void main_kernel(const float* __restrict__ z,
                                                      const float* __restrict__ emb,
                                                      const float* __restrict__ B,
                                                      float* __restrict__ out0,
                                                      float* __restrict__ out3f,
                                                      float* __restrict__ out4,
                                                      int* __restrict__ hist,
                                                      float* __restrict__ lossAcc,
                                                      int* __restrict__ flags) {
    int bid = blockIdx.x;
    int t = threadIdx.x;

    if (bid < NFILLER) {
        // ---------------- filler role: one slice ----------------
        __shared__ int fown;
        if (t == 0) fown = (atomicCAS(&flags[bid], 0, 3) == 0) ? 1 : 0;
        __syncthreads();
        if (fown) {
            float* Sb = out3f + (size_t)bid * SLICE_F;   // == 8 mod 16 B
            v4f* S4 = (v4f*)(Sb + 2);                    // aligned body
            v4f zz = {0.0f, 0.0f, 0.0f, 0.0f};
            for (int m = t; m < 49151; m += 256) S4[m] = zz;
            if (t == 0) {
                Sb[0] = 0.0f; Sb[1] = 0.0f;
                Sb[SLICE_F - 2] = 0.0f; Sb[SLICE_F - 1] = 0.0f;
            }
        }
        __syncthreads();              // waves drain vmcnt before s_barrier
        if (t == 0 && fown) {
            __threadfence();          // agent-scope release of the zero stream
            __hip_atomic_store(&flags[bid], 1,
                               __ATOMIC_RELEASE, __HIP_MEMORY_SCOPE_AGENT);
        }
        return;
    }

    // ---------------- scorer role (bit-identical math to R3..R7) ----------------
    __shared__ float sD[SPLITS][64][3];
    __shared__ int   sI[SPLITS][64][3];

    int g = bid - NFILLER;                                // row-group / slice id
    int r = t & 63;
    int split = __builtin_amdgcn_readfirstlane(t >> 6);   // uniform -> scalar loads
    int row = g * 64 + r;

    float zr[64];
    const float4* z4 = (const float4*)(z + (size_t)row * 64);
#pragma unroll
    for (int k = 0; k < 16; ++k) {
        float4 v = z4[k];
        zr[4 * k] = v.x; zr[4 * k + 1] = v.y; zr[4 * k + 2] = v.z; zr[4 * k + 3] = v.w;
    }
    float A = tree_sum64_sq(zr);

    float v0 = 3.402823466e38f, v1 = 3.402823466e38f, v2 = 3.402823466e38f;
    int i0 = 0, i1 = 0, i2 = 0;
    int jbase = split * JS;

#pragma unroll 2
    for (int jj = 0; jj < JS; ++jj) {
        int j = jbase + jj;                   // uniform (split is readfirstlane'd)
        const float4* e4 = (const float4*)(emb + (size_t)j * 64);
        float Bj = B[j];                      // uniform -> scalar load
        float acc = 0.0f;
#pragma unroll
        for (int k = 0; k < 16; ++k) {
            float4 e = e4[k];                 // uniform -> scalar loads
            acc = fmaf(zr[4 * k],     e.x, acc);
            acc = fmaf(zr[4 * k + 1], e.y, acc);
            acc = fmaf(zr[4 * k + 2], e.z, acc);
            acc = fmaf(zr[4 * k + 3], e.w, acc);
        }
        float d = (A + Bj) - 2.0f * acc;      // fma-contraction bit-identical
        top3_insert(d, j, v0, v1, v2, i0, i1, i2);
    }

    sD[split][r][0] = v0; sD[split][r][1] = v1; sD[split][r][2] = v2;
    sI[split][r][0] = i0; sI[split][r][1] = i1; sI[split][r][2] = i2;
    __syncthreads();

    if (t < 64) {                             // wave 0: zr holds row's z (split 0)
        float m0 = 3.402823466e38f, m1 = 3.402823466e38f, m2 = 3.402823466e38f;
        int j0 = 0, j1 = 0, j2 = 0;
#pragma unroll
        for (int s = 0; s < SPLITS; ++s) {    // ascending split = ascending index
#pragma unroll
            for (int u = 0; u < 3; ++u)
                top3_insert(sD[s][r][u], sI[s][r][u], m0, m1, m2, j0, j1, j2);
        }

        // ---- epilogue first (overlaps the flag wait) ----
        const float4* e0q = (const float4*)(emb + (size_t)j0 * 64);
        const float4* e1q = (const float4*)(emb + (size_t)j1 * 64);
        const float4* e2q = (const float4*)(emb + (size_t)j2 * 64);
        v4f* o4 = (v4f*)(out0 + (size_t)row * 64);

        float lsum = 0.0f;
#pragma unroll
        for (int k4 = 0; k4 < 16; ++k4) {
            float4 a = e0q[k4], b = e1q[k4], c = e2q[k4];   // vectorized gathers
            float zx = zr[4 * k4], zy = zr[4 * k4 + 1];
            float zz2 = zr[4 * k4 + 2], zw = zr[4 * k4 + 3];
            v4f st;
            float zq, df;
            zq = ((a.x + b.x) + c.x) / 3.0f; df = zq - zx;  st.x = zx  + df; lsum = fmaf(df, df, lsum);
            zq = ((a.y + b.y) + c.y) / 3.0f; df = zq - zy;  st.y = zy  + df; lsum = fmaf(df, df, lsum);
            zq = ((a.z + b.z) + c.z) / 3.0f; df = zq - zz2; st.z = zz2 + df; lsum = fmaf(df, df, lsum);
            zq = ((a.w + b.w) + c.w) / 3.0f; df = zq - zw;  st.w = zw  + df; lsum = fmaf(df, df, lsum);
            o4[k4] = st;                                    // plain store
        }

        size_t ob = (size_t)row * 3;
        out4[ob]     = (float)j0;
        out4[ob + 1] = (float)j1;
        out4[ob + 2] = (float)j2;
        atomicAdd(&hist[j0], 1);
        atomicAdd(&hist[j1], 1);
        atomicAdd(&hist[j2], 1);

#pragma unroll
        for (int off = 32; off >= 1; off >>= 1) lsum += __shfl_down(lsum, off);
        if (r == 0) atomicAdd(lossAcc, lsum);

        // ---- wait for this slice's zeros, then scatter the ones ----
        int selfown = 0;
        if (r == 0) {
            int it = 0;
            while (1) {
                int v = __hip_atomic_load(&flags[g], __ATOMIC_ACQUIRE,
                                          __HIP_MEMORY_SCOPE_AGENT);
                if (v == 1) break;
                if (v == 0 && ++it > 1500) {         // filler never ran: claim it
                    int old = atomicCAS(&flags[g], 0, 2);
                    if (old == 0) { selfown = 1; break; }
                    if (old == 1) break;
                    it = 0;                          // filler mid-write: keep waiting
                }
                __builtin_amdgcn_s_sleep(10);
            }
        }
        selfown = __shfl(selfown, 0);
        __threadfence();                             // acquire on all exit paths

        if (selfown) {
            // fallback: wave 0 writes its own slice, ones inline (R3 pattern)
            float* P = out3f + (size_t)g * SLICE_F + (size_t)r * 3072; // ==8 mod 16B
            int o0 = j0, o1 = 1024 + j1, o2 = 2048 + j2;
            P[0] = (o0 == 0) ? 1.0f : 0.0f;
            P[1] = (o0 == 1) ? 1.0f : 0.0f;
            v4f* P4 = (v4f*)(P + 2);
            for (int m = 0; m < 767; ++m) {
                int e = 2 + 4 * m;
                v4f w;
                w.x = (e     == o0 || e     == o1 || e     == o2) ? 1.0f : 0.0f;
                w.y = (e + 1 == o0 || e + 1 == o1 || e + 1 == o2) ? 1.0f : 0.0f;
                w.z = (e + 2 == o0 || e + 2 == o1 || e + 2 == o2) ? 1.0f : 0.0f;
                w.w = (e + 3 == o0 || e + 3 == o1 || e + 3 == o2) ? 1.0f : 0.0f;
                P4[m] = w;
            }
            P[3070] = (3070 == o2) ? 1.0f : 0.0f;    // o0,o1 < 3070 always
            P[3071] = (3071 == o2) ? 1.0f : 0.0f;
        } else {
            size_t sb = (size_t)row * 3072;
            out3f[sb + j0]        = 1.0f;
            out3f[sb + 1024 + j1] = 1.0f;
            out3f[sb + 2048 + j2] = 1.0f;
        }
    }
}

// ---------------------------------------------------------------------------
// Perplexity from histogram + loss finalize (unchanged).
// ---------------------------------------------------------------------------
__global__ __launch_bounds__(256) void finalize_kernel(const int* __restrict__ hist,
                                                       const float* __restrict__ lossAcc,
                                                       float* __restrict__ out1,
                                                       float* __restrict__ out2) {
    __shared__ float red[256];
    int t = threadIdx.x;
    float local = 0.0f;
    for (int b = t; b < CB; b += 256) {
        float em = (float)hist[b] / 196608.0f;
        local += em * logf(em + 1e-10f);
    }
    red[t] = local;
    __syncthreads();
    for (int s = 128; s >= 1; s >>= 1) {
        if (t < s) red[t] += red[t + s];
        __syncthreads();
    }
    if (t == 0) {
        *out2 = expf(-red[0]);
        float m = *lossAcc / 4194304.0f;
        *out1 = 0.25f * m + m;     // BETA_C*mse + mse
    }
}

extern "C" void kernel_launch(void* const* d_in, const int* in_sizes, int n_in,
                              void* d_out, int out_size, void* d_ws, size_t ws_size,
                              hipStream_t stream) {
    const float* z   = (const float*)d_in[0];   // [16,64,64,64] -> 65536 x 64
    const float* emb = (const float*)d_in[1];   // [1024, 64]

    float* out  = (float*)d_out;
    float* out0 = out;                                    // z_q_st  4194304
    float* out1 = out + 4194304;                          // loss    1
    float* out2 = out + 4194305;                          // perplexity 1
    float* out3 = out + 4194306;                          // encodings 201326592
    float* out4 = out + 4194306 + 201326592ll;            // topk_idx (as float) 196608

    int*   hist    = (int*)d_ws;                          // 1024 ints @ 0
    float* lossAcc = (float*)((char*)d_ws + 4096);        // 1 float
    float* B       = (float*)((char*)d_ws + 8192);        // 1024 floats
    int*   flags   = (int*)((char*)d_ws + 12288);         // 1024 ints (slice flags)

    prep_kernel<<<4, 256, 0, stream>>>(emb, B, hist, lossAcc, flags);
    main_kernel<<<NFILLER + N_ROWS / 64, 256, 0, stream>>>(z, emb, B, out0, out3,
                                                           out4, hist, lossAcc, flags);
    finalize_kernel<<<1, 256, 0, stream>>>(hist, lossAcc, out1, out2);
}

// Round 10
// 1195.918 us; speedup vs baseline: 1.8162x; 1.8162x over previous
//
#include <hip/hip_runtime.h>
#include <math.h>

#define N_ROWS 65536
#define CB 1024

typedef float v4f __attribute__((ext_vector_type(4)));

// ---------------------------------------------------------------------------
// Exact emulation of numpy's pairwise_sum for n=64 fp32 (AVX-512 path).
// fp contract OFF so the squares are not fused into the adds.
// ---------------------------------------------------------------------------
__device__ __forceinline__ float tree_sum64_sq(const float* x) {
#pragma clang fp contract(off)
    float sq[64];
#pragma unroll
    for (int i = 0; i < 64; ++i) sq[i] = x[i] * x[i];
    float s[16];
#pragma unroll
    for (int l = 0; l < 16; ++l) s[l] = (sq[l] + sq[l + 16]) + (sq[l + 32] + sq[l + 48]);
    float t[8];
#pragma unroll
    for (int l = 0; l < 8; ++l) t[l] = s[l] + s[l + 8];
    float u[4];
#pragma unroll
    for (int l = 0; l < 4; ++l) u[l] = t[l] + t[l + 4];
    float v0 = u[0] + u[2];
    float v1 = u[1] + u[3];
    return v0 + v1;
}

// sorted-triple insert, strict < (ties keep earlier-inserted = lower index,
// matching jax.lax.top_k stable tie-breaking when fed in ascending index order)
__device__ __forceinline__ void top3_insert(float d, int j,
                                            float& v0, float& v1, float& v2,
                                            int& i0, int& i1, int& i2) {
    bool b0 = d < v0, b1 = d < v1, b2 = d < v2;
    v2 = b1 ? v1 : (b2 ? d : v2);
    i2 = b1 ? i1 : (b2 ? j : i2);
    v1 = b0 ? v0 : (b1 ? d : v1);
    i1 = b0 ? i0 : (b1 ? j : i1);
    v0 = b0 ? d : v0;
    i0 = b0 ? j : i0;
}

// ---------------------------------------------------------------------------
// B[j] = np.sum(emb[j]**2) (exact tree emulation) + zero hist/lossAcc.
// ---------------------------------------------------------------------------
__global__ __launch_bounds__(256) void prep_kernel(const float* __restrict__ emb,
                                                   float* __restrict__ B,
                                                   int* __restrict__ hist,
                                                   float* __restrict__ lossAcc) {
    int j = blockIdx.x * 256 + threadIdx.x;
    if (j >= CB) return;
    float e[64];
    const float4* e4 = (const float4*)(emb + (size_t)j * 64);
#pragma unroll
    for (int k = 0; k < 16; ++k) {
        float4 v = e4[k];
        e[4 * k] = v.x; e[4 * k + 1] = v.y; e[4 * k + 2] = v.z; e[4 * k + 3] = v.w;
    }
    B[j] = tree_sum64_sq(e);
    hist[j] = 0;
    if (j == 0) *lossAcc = 0.0f;
}

// ---------------------------------------------------------------------------
// Scorer v2.1: ONE THREAD PER ROW, emb streamed through LDS.
//
// R9 bug fixed here: a chunk is 64 entries x 64 floats = 1024 float4s, but
// R9 staged only 256 (one per thread) -> 3/4 of eL was stale garbage ->
// wrong top-3 -> perplexity absmax 738. Now each thread stages FOUR float4s
// (pre[4], indices c*1024 + q*256 + t), covering the whole chunk; prefetch
// depth 4 also hides the staging latency better.
//
// Design rationale (R8 post-mortem): the 4-way-split scorer was SMEM-latency
// bound (~215 us vs 54 us VALU floor): per j, 4x s_load_dwordx16 (~200 cy,
// emb misses scalar L1) cover only 128 cy of FMA. Here the inner loop reads
// emb via UNIFORM-address ds_read_b128 (broadcast, conflict-free, DS pipe
// overlaps VALU issue); two j's per iteration = two independent fmaf chains
// -> 2-cy issue despite the 4-cy dependent-FMA latency.
//
// Bit-exactness: per-(row,j) chain is the same sequential-k fmaf chain on
// the same values; insert order ascending j; A/Bj terms identical; epilogue,
// lsum wave-reduce shape (64 consecutive rows, 1 atomic/wave, 1024 total),
// ones/out4/hist identical to the passing rounds.
// ---------------------------------------------------------------------------
__global__ __launch_bounds__(256) void score_kernel(const float* __restrict__ z,
                                                    const float* __restrict__ emb,
                                                    const float* __restrict__ B,
                                                    float* __restrict__ out0,
                                                    float* __restrict__ out3f,
                                                    float* __restrict__ out4,
                                                    int* __restrict__ hist,
                                                    float* __restrict__ lossAcc) {
    __shared__ float eL[4096];        // one 64-entry emb chunk (16 KB)
    __shared__ float eB[64];          // B values for the chunk

    int t = threadIdx.x;
    int row = blockIdx.x * 256 + t;

    float zr[64];
    const float4* z4 = (const float4*)(z + (size_t)row * 64);
#pragma unroll
    for (int k = 0; k < 16; ++k) {
        float4 v = z4[k];
        zr[4 * k] = v.x; zr[4 * k + 1] = v.y; zr[4 * k + 2] = v.z; zr[4 * k + 3] = v.w;
    }
    float A = tree_sum64_sq(zr);

    float v0 = 3.402823466e38f, v1 = 3.402823466e38f, v2 = 3.402823466e38f;
    int i0 = 0, i1 = 0, i2 = 0;

    const v4f* emb4 = (const v4f*)emb;              // 16384 float4s total
    v4f pre[4];                                     // chunk staging prefetch:
#pragma unroll
    for (int q = 0; q < 4; ++q)                     // 4 float4s/thread =
        pre[q] = emb4[q * 256 + t];                 // full 1024-float4 chunk
    float preB = (t < 64) ? B[t] : 0.0f;

    for (int c = 0; c < 16; ++c) {
        __syncthreads();                            // prev chunk fully consumed
#pragma unroll
        for (int q = 0; q < 4; ++q)
            ((v4f*)eL)[q * 256 + t] = pre[q];
        if (t < 64) eB[t] = preB;
        __syncthreads();                            // chunk ready
        if (c < 15) {                               // issue next staging early;
#pragma unroll
            for (int q = 0; q < 4; ++q)             // drains under the compute
                pre[q] = emb4[(c + 1) * 1024 + q * 256 + t];
            if (t < 64) preB = B[(c + 1) * 64 + t];
        }

        for (int jj = 0; jj < 64; jj += 2) {        // two independent chains
            const float* e0 = eL + jj * 64;
            const float* e1 = e0 + 64;
            float Bj0 = eB[jj];
            float Bj1 = eB[jj + 1];
            float acc0 = 0.0f, acc1 = 0.0f;
#pragma unroll
            for (int k4 = 0; k4 < 16; ++k4) {
                v4f a = *(const v4f*)(e0 + 4 * k4); // uniform addr -> broadcast
                v4f b = *(const v4f*)(e1 + 4 * k4);
                acc0 = fmaf(zr[4 * k4],     a.x, acc0);
                acc1 = fmaf(zr[4 * k4],     b.x, acc1);
                acc0 = fmaf(zr[4 * k4 + 1], a.y, acc0);
                acc1 = fmaf(zr[4 * k4 + 1], b.y, acc1);
                acc0 = fmaf(zr[4 * k4 + 2], a.z, acc0);
                acc1 = fmaf(zr[4 * k4 + 2], b.z, acc1);
                acc0 = fmaf(zr[4 * k4 + 3], a.w, acc0);
                acc1 = fmaf(zr[4 * k4 + 3], b.w, acc1);
            }
            int j = c * 64 + jj;
            float d0 = (A + Bj0) - 2.0f * acc0;     // 2*acc exact -> contraction
            float d1 = (A + Bj1) - 2.0f * acc1;     // bit-identical
            top3_insert(d0, j,     v0, v1, v2, i0, i1, i2);
            top3_insert(d1, j + 1, v0, v1, v2, i0, i1, i2);
        }
    }

    int j0 = i0, j1 = i1, j2 = i2;

    // ---- one-hot "one" positions (zeros laid down by the prior memset) ----
    size_t sb = (size_t)row * 3072;
    out3f[sb + j0]        = 1.0f;
    out3f[sb + 1024 + j1] = 1.0f;
    out3f[sb + 2048 + j2] = 1.0f;

    // ---- epilogue: z_q_st + loss partial (identical FP ops per row) ----
    const float4* e0q = (const float4*)(emb + (size_t)j0 * 64);
    const float4* e1q = (const float4*)(emb + (size_t)j1 * 64);
    const float4* e2q = (const float4*)(emb + (size_t)j2 * 64);
    v4f* o4 = (v4f*)(out0 + (size_t)row * 64);

    float lsum = 0.0f;
#pragma unroll
    for (int k4 = 0; k4 < 16; ++k4) {
        float4 a = e0q[k4], b = e1q[k4], cc = e2q[k4];
        float zx = zr[4 * k4], zy = zr[4 * k4 + 1];
        float zz = zr[4 * k4 + 2], zw = zr[4 * k4 + 3];
        v4f st;
        float zq, df;
        zq = ((a.x + b.x) + cc.x) / 3.0f; df = zq - zx; st.x = zx + df; lsum = fmaf(df, df, lsum);
        zq = ((a.y + b.y) + cc.y) / 3.0f; df = zq - zy; st.y = zy + df; lsum = fmaf(df, df, lsum);
        zq = ((a.z + b.z) + cc.z) / 3.0f; df = zq - zz; st.z = zz + df; lsum = fmaf(df, df, lsum);
        zq = ((a.w + b.w) + cc.w) / 3.0f; df = zq - zw; st.w = zw + df; lsum = fmaf(df, df, lsum);
        o4[k4] = st;                                // plain store
    }

    size_t ob = (size_t)row * 3;
    out4[ob]     = (float)j0;
    out4[ob + 1] = (float)j1;
    out4[ob + 2] = (float)j2;
    atomicAdd(&hist[j0], 1);
    atomicAdd(&hist[j1], 1);
    atomicAdd(&hist[j2], 1);

    // wave-level reduce of loss partial, one atomic per wave (1024 total,
    // 64 consecutive rows per wave — same shape as all passing rounds)
#pragma unroll
    for (int off = 32; off >= 1; off >>= 1) lsum += __shfl_down(lsum, off);
    if ((t & 63) == 0) atomicAdd(lossAcc, lsum);
}

// ---------------------------------------------------------------------------
// Perplexity from histogram + loss finalize (unchanged).
// ---------------------------------------------------------------------------
__global__ __launch_bounds__(256) void finalize_kernel(const int* __restrict__ hist,
                                                       const float* __restrict__ lossAcc,
                                                       float* __restrict__ out1,
                                                       float* __restrict__ out2) {
    __shared__ float red[256];
    int t = threadIdx.x;
    float local = 0.0f;
    for (int b = t; b < CB; b += 256) {
        float em = (float)hist[b] / 196608.0f;
        local += em * logf(em + 1e-10f);
    }
    red[t] = local;
    __syncthreads();
    for (int s = 128; s >= 1; s >>= 1) {
        if (t < s) red[t] += red[t + s];
        __syncthreads();
    }
    if (t == 0) {
        *out2 = expf(-red[0]);
        float m = *lossAcc / 4194304.0f;
        *out1 = 0.25f * m + m;     // BETA_C*mse + mse
    }
}

extern "C" void kernel_launch(void* const* d_in, const int* in_sizes, int n_in,
                              void* d_out, int out_size, void* d_ws, size_t ws_size,
                              hipStream_t stream) {
    const float* z   = (const float*)d_in[0];   // [16,64,64,64] -> 65536 x 64
    const float* emb = (const float*)d_in[1];   // [1024, 64]

    float* out  = (float*)d_out;
    float* out0 = out;                                    // z_q_st  4194304
    float* out1 = out + 4194304;                          // loss    1
    float* out2 = out + 4194305;                          // perplexity 1
    float* out3 = out + 4194306;                          // encodings 201326592
    float* out4 = out + 4194306 + 201326592ll;            // topk_idx (as float) 196608

    int*   hist    = (int*)d_ws;                          // 1024 ints @ 0
    float* lossAcc = (float*)((char*)d_ws + 4096);        // 1 float
    float* B       = (float*)((char*)d_ws + 8192);        // 1024 floats

    prep_kernel<<<4, 256, 0, stream>>>(emb, B, hist, lossAcc);
    // 805 MB zero fill at the measured pure-write wall (~2.5 TB/s). Serial
    // with score (stream order also guarantees zeros-before-ones).
    hipMemsetAsync(out3, 0, (size_t)N_ROWS * 3 * CB * sizeof(float), stream);
    score_kernel<<<N_ROWS / 256, 256, 0, stream>>>(z, emb, B, out0, out3, out4,
                                                   hist, lossAcc);
    finalize_kernel<<<1, 256, 0, stream>>>(hist, lossAcc, out1, out2);
}